// Round 3
// baseline (212.354 us; speedup 1.0000x reference)
//
#include <hip/hip_runtime.h>
#include <hip/hip_bf16.h>

// B=8, NH=8, KS=VS=64, HW=1024, C=1536, GROUPS=24. pair = b*8+h (64 pairs).
// Pipeline: gn_partial -> pack(K,V bf16, stats fused) -> attn (S^T flash).

typedef __attribute__((ext_vector_type(8))) short bf16x8;
typedef __attribute__((ext_vector_type(4))) float f32x4;
typedef unsigned short u16;

union U8 { bf16x8 v; u16 s[8]; };

__device__ __forceinline__ u16 f2bf(float f) {
    union { float f; unsigned u; } a; a.f = f;
    unsigned u = a.u;
    return (u16)((u + 0x7fffu + ((u >> 16) & 1u)) >> 16);  // RNE
}

// ---- Kernel 1: partial GN stats. 1536 blocks = 8 slices per (b,group).
__global__ __launch_bounds__(256) void gn_partial(const float* __restrict__ x,
                                                  float* __restrict__ partials) {
    int blk = blockIdx.x;                         // 0..1535
    const float4* p = (const float4*)(x + (size_t)blk * 8192);
    int t = threadIdx.x;
    float s1a = 0.f, s2a = 0.f, s1b = 0.f, s2b = 0.f;
#pragma unroll
    for (int i = 0; i < 8; i += 2) {
        float4 va = p[t + i * 256];
        float4 vb = p[t + (i + 1) * 256];
        s1a += va.x + va.y + va.z + va.w;
        s2a += va.x * va.x + va.y * va.y + va.z * va.z + va.w * va.w;
        s1b += vb.x + vb.y + vb.z + vb.w;
        s2b += vb.x * vb.x + vb.y * vb.y + vb.z * vb.z + vb.w * vb.w;
    }
    float s1 = s1a + s1b, s2 = s2a + s2b;
    for (int off = 32; off > 0; off >>= 1) {
        s1 += __shfl_down(s1, off);
        s2 += __shfl_down(s2, off);
    }
    __shared__ float a1[4], a2[4];
    int wave = t >> 6, lane = t & 63;
    if (lane == 0) { a1[wave] = s1; a2[wave] = s2; }
    __syncthreads();
    if (t == 0) {
        partials[blk * 2 + 0] = a1[0] + a1[1] + a1[2] + a1[3];
        partials[blk * 2 + 1] = a2[0] + a2[1] + a2[2] + a2[3];
    }
}

__device__ __forceinline__ void group_stats(const float* __restrict__ partials,
                                            int bg, float& mean, float& rstd) {
    float s1 = 0.f, s2 = 0.f;
#pragma unroll
    for (int j = 0; j < 8; ++j) {
        s1 += partials[(bg * 8 + j) * 2 + 0];
        s2 += partials[(bg * 8 + j) * 2 + 1];
    }
    mean = s1 * (1.f / 65536.f);
    float var = s2 * (1.f / 65536.f) - mean * mean;
    rstd = rsqrtf(var + 1e-5f);
}

// ---- Kernel 2: normalize + bf16 pack of K (as [s][c]) and V (as [c][s]).
// Grid (16,64). Stats finalized inline (uniform scalar loads).
__global__ __launch_bounds__(256) void pack_kernel(
    const float* __restrict__ x, const float* __restrict__ gamma,
    const float* __restrict__ beta, const float* __restrict__ partials,
    u16* __restrict__ Kn, u16* __restrict__ Vn)
{
    const int st = blockIdx.x, pair = blockIdx.y;
    const int b = pair >> 3, h = pair & 7;
    const float* xb = x + (size_t)b * 1536 * 1024;
    float mk, rk, mv, rv;
    group_stats(partials, b * 24 + 3 * h + 0, mk, rk);
    group_stats(partials, b * 24 + 3 * h + 2, mv, rv);

    const int t = threadIdx.x;
    // K: transpose-pack. c0 on lanes (coalesced stores), s on upper bits.
    {
        const int c0 = (t & 15) * 4;
        const int sg = st * 64 + (t >> 4) * 4;
        float4 rr[4]; float wsc[4], bsc[4];
#pragma unroll
        for (int dc = 0; dc < 4; ++dc) {
            int cg = h * 192 + c0 + dc;
            rr[dc] = *(const float4*)(xb + (size_t)cg * 1024 + sg);
            wsc[dc] = gamma[cg] * rk;
            bsc[dc] = beta[cg] - mk * wsc[dc];
        }
        u16* dp = Kn + (size_t)pair * 65536 + (size_t)sg * 64 + c0;
        ushort4 o;
        o.x = f2bf(rr[0].x * wsc[0] + bsc[0]); o.y = f2bf(rr[1].x * wsc[1] + bsc[1]);
        o.z = f2bf(rr[2].x * wsc[2] + bsc[2]); o.w = f2bf(rr[3].x * wsc[3] + bsc[3]);
        *(ushort4*)(dp +   0) = o;
        o.x = f2bf(rr[0].y * wsc[0] + bsc[0]); o.y = f2bf(rr[1].y * wsc[1] + bsc[1]);
        o.z = f2bf(rr[2].y * wsc[2] + bsc[2]); o.w = f2bf(rr[3].y * wsc[3] + bsc[3]);
        *(ushort4*)(dp +  64) = o;
        o.x = f2bf(rr[0].z * wsc[0] + bsc[0]); o.y = f2bf(rr[1].z * wsc[1] + bsc[1]);
        o.z = f2bf(rr[2].z * wsc[2] + bsc[2]); o.w = f2bf(rr[3].z * wsc[3] + bsc[3]);
        *(ushort4*)(dp + 128) = o;
        o.x = f2bf(rr[0].w * wsc[0] + bsc[0]); o.y = f2bf(rr[1].w * wsc[1] + bsc[1]);
        o.z = f2bf(rr[2].w * wsc[2] + bsc[2]); o.w = f2bf(rr[3].w * wsc[3] + bsc[3]);
        *(ushort4*)(dp + 192) = o;
    }
    // V: native layout, pure elementwise.
    {
        const int sg = st * 64 + (t & 15) * 4;
#pragma unroll
        for (int p = 0; p < 4; ++p) {
            int c = p * 16 + (t >> 4);
            int cg = h * 192 + 128 + c;
            float4 vv = *(const float4*)(xb + (size_t)cg * 1024 + sg);
            float wsc = gamma[cg] * rv;
            float bsc = beta[cg] - mv * wsc;
            ushort4 o;
            o.x = f2bf(vv.x * wsc + bsc); o.y = f2bf(vv.y * wsc + bsc);
            o.z = f2bf(vv.z * wsc + bsc); o.w = f2bf(vv.w * wsc + bsc);
            *(ushort4*)(Vn + (size_t)pair * 65536 + (size_t)c * 1024 + sg) = o;
        }
    }
}

// ---- Kernel 3: flash attention with S^T layout. Grid 1024 (1D):
// bid = qt*64 + pair  (bid%8 = pair%8 -> all 16 blocks of a pair on one XCD).
// 256 thr = 4 waves; each wave owns 16 queries (on lane&15), all softmax state
// is one scalar per lane. Only P goes through (wave-private) LDS.
__global__ __launch_bounds__(256, 4) void attn_kernel(
    const float* __restrict__ x, const float* __restrict__ gamma,
    const float* __restrict__ beta, const float* __restrict__ partials,
    const u16* __restrict__ Kn, const u16* __restrict__ Vn,
    float* __restrict__ out)
{
    const int bid = blockIdx.x;
    const int qt = bid >> 6;        // 0..15
    const int pair = bid & 63;
    const int b = pair >> 3, h = pair & 7;

    const int tid = threadIdx.x;
    const int w = tid >> 6;
    const int lane = tid & 63;
    const int grp = lane >> 4;      // quad
    const int li  = lane & 15;

    __shared__ alignas(16) u16 Pt[4][16][72];   // per-wave P [q=li][key]

    const u16* Kp = Kn + (size_t)pair * 65536;
    const u16* Vp = Vn + (size_t)pair * 65536;
    const int qglobal = qt * 64 + w * 16 + li;

    // ---- Q stats (uniform) + inline normalize of this wave's 16 queries.
    float mq, rq;
    group_stats(partials, b * 24 + 3 * h + 1, mq, rq);
    const float* xb = x + (size_t)b * 1536 * 1024;

    bf16x8 bq[2];
#pragma unroll
    for (int h2 = 0; h2 < 2; ++h2) {
        U8 u;
#pragma unroll
        for (int j = 0; j < 8; ++j) {
            int cg = h * 192 + 64 + h2 * 32 + grp * 8 + j;
            float v = xb[(size_t)cg * 1024 + qglobal];
            float wsc = gamma[cg] * rq;
            float bsc = beta[cg] - mq * wsc;
            u.s[j] = f2bf(v * wsc + bsc);
        }
        bq[h2] = u.v;
    }

    f32x4 oacc[4];
#pragma unroll
    for (int vf = 0; vf < 4; ++vf) oacc[vf] = f32x4{0.f, 0.f, 0.f, 0.f};
    float mrun = -1e30f, lrun = 0.f;

    for (int kt = 0; kt < 16; ++kt) {
        // ---- S^T = K Q^T : rows=keys (grp*4+reg per kf), cols=q (li)
        f32x4 sf[4];
#pragma unroll
        for (int kf = 0; kf < 4; ++kf) {
            const u16* kr = Kp + (size_t)(kt * 64 + kf * 16 + li) * 64 + grp * 8;
            f32x4 acc = f32x4{0.f, 0.f, 0.f, 0.f};
            bf16x8 ak0 = *(const bf16x8*)(kr);
            acc = __builtin_amdgcn_mfma_f32_16x16x32_bf16(ak0, bq[0], acc, 0, 0, 0);
            bf16x8 ak1 = *(const bf16x8*)(kr + 32);
            acc = __builtin_amdgcn_mfma_f32_16x16x32_bf16(ak1, bq[1], acc, 0, 0, 0);
            sf[kf] = acc;
        }

        // ---- online softmax over keys: in-register + 2 cross-quad shuffles.
        float mx = sf[0][0];
#pragma unroll
        for (int kf = 0; kf < 4; ++kf)
#pragma unroll
            for (int r = 0; r < 4; ++r)
                mx = fmaxf(mx, sf[kf][r]);
        mx = fmaxf(mx, __shfl_xor(mx, 16));
        mx = fmaxf(mx, __shfl_xor(mx, 32));
        mx *= 0.125f;

        float mnew = fmaxf(mrun, mx);
        float alpha = __expf(mrun - mnew);
        mrun = mnew;

        float sum = 0.f;
#pragma unroll
        for (int kf = 0; kf < 4; ++kf) {
            ushort4 o;
            float p0 = __expf(__builtin_fmaf(sf[kf][0], 0.125f, -mnew));
            float p1 = __expf(__builtin_fmaf(sf[kf][1], 0.125f, -mnew));
            float p2 = __expf(__builtin_fmaf(sf[kf][2], 0.125f, -mnew));
            float p3 = __expf(__builtin_fmaf(sf[kf][3], 0.125f, -mnew));
            sum += (p0 + p1) + (p2 + p3);
            o.x = f2bf(p0); o.y = f2bf(p1); o.z = f2bf(p2); o.w = f2bf(p3);
            *(ushort4*)&Pt[w][li][kf * 16 + grp * 4] = o;   // key = kf*16+grp*4+r
        }
        sum += __shfl_xor(sum, 16);
        sum += __shfl_xor(sum, 32);
        lrun = lrun * alpha + sum;
#pragma unroll
        for (int vf = 0; vf < 4; ++vf)
#pragma unroll
            for (int r = 0; r < 4; ++r)
                oacc[vf][r] *= alpha;

        // ---- O^T += V P : A=V (m=v, k=key), B=P (n=q=li, k=key).
        // D rows = v (grp*4+reg per vf), cols = q (li): alpha/l are per-lane scalars.
#pragma unroll
        for (int kh = 0; kh < 2; ++kh) {
            bf16x8 bp = *(const bf16x8*)&Pt[w][li][kh * 32 + grp * 8];
#pragma unroll
            for (int vf = 0; vf < 4; ++vf) {
                bf16x8 av = *(const bf16x8*)(Vp + (size_t)(vf * 16 + li) * 1024
                                             + kt * 64 + kh * 32 + grp * 8);
                oacc[vf] = __builtin_amdgcn_mfma_f32_16x16x32_bf16(av, bp, oacc[vf], 0, 0, 0);
            }
        }
    }

    // ---- epilogue: per-lane scale, directly coalesced stores (cols=q=li).
    float invl = 1.f / lrun;
    float* ob = out + (size_t)pair * 65536 + qglobal;
#pragma unroll
    for (int vf = 0; vf < 4; ++vf)
#pragma unroll
        for (int r = 0; r < 4; ++r) {
            int v = vf * 16 + grp * 4 + r;
            ob[(size_t)v * 1024] = oacc[vf][r] * invl;
        }
}

extern "C" void kernel_launch(void* const* d_in, const int* in_sizes, int n_in,
                              void* d_out, int out_size, void* d_ws, size_t ws_size,
                              hipStream_t stream) {
    const float* x     = (const float*)d_in[0];
    const float* gamma = (const float*)d_in[1];
    const float* beta  = (const float*)d_in[2];
    float* out = (float*)d_out;

    float* partials = (float*)d_ws;                       // 3072 f32
    u16* Kn = (u16*)((char*)d_ws + 65536);                // 8.4 MB
    u16* Vn = Kn + (size_t)64 * 65536;                    // 8.4 MB (total ~16.8 MB)

    gn_partial<<<1536, 256, 0, stream>>>(x, partials);
    pack_kernel<<<dim3(16, 64), 256, 0, stream>>>(x, gamma, beta, partials, Kn, Vn);
    attn_kernel<<<1024, 256, 0, stream>>>(x, gamma, beta, partials, Kn, Vn, out);
}

// Round 4
// 165.379 us; speedup vs baseline: 1.2840x; 1.2840x over previous
//
#include <hip/hip_runtime.h>
#include <hip/hip_bf16.h>

// B=8, NH=8, KS=VS=64, HW=1024, C=1536, GROUPS=24. pair = b*8+h (64 pairs).
// Pipeline: gn_partial -> pack(K,V bf16, stats fused) -> attn (S^T flash,
// 1-wave blocks, 32 q/wave, register double-buffered K/V frags).

typedef __attribute__((ext_vector_type(8))) short bf16x8;
typedef __attribute__((ext_vector_type(4))) float f32x4;
typedef unsigned short u16;

union U8 { bf16x8 v; u16 s[8]; };

#define SM_SCALE 0.18033688f   // 0.125 * log2(e)

__device__ __forceinline__ u16 f2bf(float f) {
    union { float f; unsigned u; } a; a.f = f;
    unsigned u = a.u;
    return (u16)((u + 0x7fffu + ((u >> 16) & 1u)) >> 16);  // RNE
}

// ---- Kernel 1: partial GN stats. 1536 blocks = 8 slices per (b,group).
__global__ __launch_bounds__(256) void gn_partial(const float* __restrict__ x,
                                                  float* __restrict__ partials) {
    int blk = blockIdx.x;                         // 0..1535
    const float4* p = (const float4*)(x + (size_t)blk * 8192);
    int t = threadIdx.x;
    float s1a = 0.f, s2a = 0.f, s1b = 0.f, s2b = 0.f;
#pragma unroll
    for (int i = 0; i < 8; i += 2) {
        float4 va = p[t + i * 256];
        float4 vb = p[t + (i + 1) * 256];
        s1a += va.x + va.y + va.z + va.w;
        s2a += va.x * va.x + va.y * va.y + va.z * va.z + va.w * va.w;
        s1b += vb.x + vb.y + vb.z + vb.w;
        s2b += vb.x * vb.x + vb.y * vb.y + vb.z * vb.z + vb.w * vb.w;
    }
    float s1 = s1a + s1b, s2 = s2a + s2b;
    for (int off = 32; off > 0; off >>= 1) {
        s1 += __shfl_down(s1, off);
        s2 += __shfl_down(s2, off);
    }
    __shared__ float a1[4], a2[4];
    int wave = t >> 6, lane = t & 63;
    if (lane == 0) { a1[wave] = s1; a2[wave] = s2; }
    __syncthreads();
    if (t == 0) {
        partials[blk * 2 + 0] = a1[0] + a1[1] + a1[2] + a1[3];
        partials[blk * 2 + 1] = a2[0] + a2[1] + a2[2] + a2[3];
    }
}

__device__ __forceinline__ void group_stats(const float* __restrict__ partials,
                                            int bg, float& mean, float& rstd) {
    float s1 = 0.f, s2 = 0.f;
#pragma unroll
    for (int j = 0; j < 8; ++j) {
        s1 += partials[(bg * 8 + j) * 2 + 0];
        s2 += partials[(bg * 8 + j) * 2 + 1];
    }
    mean = s1 * (1.f / 65536.f);
    float var = s2 * (1.f / 65536.f) - mean * mean;
    rstd = rsqrtf(var + 1e-5f);
}

// ---- Kernel 2: normalize + bf16 pack of K (as [s][c]) and V (as [c][s]).
// 1D grid 1024: bid = st*64 + pair  -> bid%8 = pair%8, same XCD as attn's
// blocks for this pair (L2 write->read locality).
__global__ __launch_bounds__(256) void pack_kernel(
    const float* __restrict__ x, const float* __restrict__ gamma,
    const float* __restrict__ beta, const float* __restrict__ partials,
    u16* __restrict__ Kn, u16* __restrict__ Vn)
{
    const int st = blockIdx.x >> 6, pair = blockIdx.x & 63;
    const int b = pair >> 3, h = pair & 7;
    const float* xb = x + (size_t)b * 1536 * 1024;
    float mk, rk, mv, rv;
    group_stats(partials, b * 24 + 3 * h + 0, mk, rk);
    group_stats(partials, b * 24 + 3 * h + 2, mv, rv);

    const int t = threadIdx.x;
    // K: transpose-pack. c0 on lanes (coalesced stores), s on upper bits.
    {
        const int c0 = (t & 15) * 4;
        const int sg = st * 64 + (t >> 4) * 4;
        float4 rr[4]; float wsc[4], bsc[4];
#pragma unroll
        for (int dc = 0; dc < 4; ++dc) {
            int cg = h * 192 + c0 + dc;
            rr[dc] = *(const float4*)(xb + (size_t)cg * 1024 + sg);
            wsc[dc] = gamma[cg] * rk;
            bsc[dc] = beta[cg] - mk * wsc[dc];
        }
        u16* dp = Kn + (size_t)pair * 65536 + (size_t)sg * 64 + c0;
        ushort4 o;
        o.x = f2bf(rr[0].x * wsc[0] + bsc[0]); o.y = f2bf(rr[1].x * wsc[1] + bsc[1]);
        o.z = f2bf(rr[2].x * wsc[2] + bsc[2]); o.w = f2bf(rr[3].x * wsc[3] + bsc[3]);
        *(ushort4*)(dp +   0) = o;
        o.x = f2bf(rr[0].y * wsc[0] + bsc[0]); o.y = f2bf(rr[1].y * wsc[1] + bsc[1]);
        o.z = f2bf(rr[2].y * wsc[2] + bsc[2]); o.w = f2bf(rr[3].y * wsc[3] + bsc[3]);
        *(ushort4*)(dp +  64) = o;
        o.x = f2bf(rr[0].z * wsc[0] + bsc[0]); o.y = f2bf(rr[1].z * wsc[1] + bsc[1]);
        o.z = f2bf(rr[2].z * wsc[2] + bsc[2]); o.w = f2bf(rr[3].z * wsc[3] + bsc[3]);
        *(ushort4*)(dp + 128) = o;
        o.x = f2bf(rr[0].w * wsc[0] + bsc[0]); o.y = f2bf(rr[1].w * wsc[1] + bsc[1]);
        o.z = f2bf(rr[2].w * wsc[2] + bsc[2]); o.w = f2bf(rr[3].w * wsc[3] + bsc[3]);
        *(ushort4*)(dp + 192) = o;
    }
    // V: native layout, pure elementwise.
    {
        const int sg = st * 64 + (t & 15) * 4;
#pragma unroll
        for (int p = 0; p < 4; ++p) {
            int c = p * 16 + (t >> 4);
            int cg = h * 192 + 128 + c;
            float4 vv = *(const float4*)(xb + (size_t)cg * 1024 + sg);
            float wsc = gamma[cg] * rv;
            float bsc = beta[cg] - mv * wsc;
            ushort4 o;
            o.x = f2bf(vv.x * wsc + bsc); o.y = f2bf(vv.y * wsc + bsc);
            o.z = f2bf(vv.z * wsc + bsc); o.w = f2bf(vv.w * wsc + bsc);
            *(ushort4*)(Vn + (size_t)pair * 65536 + (size_t)c * 1024 + sg) = o;
        }
    }
}

// ---- Kernel 3: flash attention, S^T layout, 1-wave blocks, 32 q/wave.
// Grid 2048: bid = qt*64 + pair (qt 0..31) -> bid%8 = pair%8 (XCD locality).
// All softmax state is per-lane scalar (one per qf). Register double-buffer
// prefetches next kt's K/V fragments under the current softmax/PV.
__global__ __launch_bounds__(64, 2) void attn_kernel(
    const float* __restrict__ x, const float* __restrict__ gamma,
    const float* __restrict__ beta, const float* __restrict__ partials,
    const u16* __restrict__ Kn, const u16* __restrict__ Vn,
    float* __restrict__ out)
{
    const int bid = blockIdx.x;
    const int qt = bid >> 6;        // 0..31
    const int pair = bid & 63;
    const int b = pair >> 3, h = pair & 7;

    const int lane = threadIdx.x & 63;
    const int grp = lane >> 4;      // quad
    const int li  = lane & 15;

    __shared__ alignas(16) u16 Pt[2][16][72];   // P^T-source [qf][q=li][key]

    const u16* Kp = Kn + (size_t)pair * 65536;
    const u16* Vp = Vn + (size_t)pair * 65536;

    // ---- Q stats (uniform) + inline normalize of this wave's 32 queries.
    float mq, rq;
    group_stats(partials, b * 24 + 3 * h + 1, mq, rq);
    const float* xb = x + (size_t)b * 1536 * 1024;

    bf16x8 bq[2][2];                // [qf][kh]  B[n=q(li)][k=c]
#pragma unroll
    for (int qf = 0; qf < 2; ++qf)
#pragma unroll
        for (int kh = 0; kh < 2; ++kh) {
            U8 u;
            int q = qt * 32 + qf * 16 + li;
#pragma unroll
            for (int j = 0; j < 8; ++j) {
                int cg = h * 192 + 64 + kh * 32 + grp * 8 + j;
                float v = xb[(size_t)cg * 1024 + q];
                float wsc = gamma[cg] * rq;
                float bsc = beta[cg] - mq * wsc;
                u.s[j] = f2bf(v * wsc + bsc);
            }
            bq[qf][kh] = u.v;
        }

    f32x4 oacc[2][4];               // [qf][vf]  O^T rows=v, cols=q(li)
#pragma unroll
    for (int qf = 0; qf < 2; ++qf)
#pragma unroll
        for (int vf = 0; vf < 4; ++vf) oacc[qf][vf] = f32x4{0.f, 0.f, 0.f, 0.f};
    float mrun[2] = {-1e30f, -1e30f}, lrun[2] = {0.f, 0.f};

    bf16x8 ak[2][4][2], av[2][4][2];   // double-buffered frags
#pragma unroll
    for (int kf = 0; kf < 4; ++kf)
#pragma unroll
        for (int kh = 0; kh < 2; ++kh) {
            ak[0][kf][kh] = *(const bf16x8*)(Kp + (size_t)(kf * 16 + li) * 64 + kh * 32 + grp * 8);
            av[0][kf][kh] = *(const bf16x8*)(Vp + (size_t)(kf * 16 + li) * 1024 + kh * 32 + grp * 8);
        }

#pragma unroll 2
    for (int kt = 0; kt < 16; ++kt) {
        const int cb = kt & 1, nb = cb ^ 1;
        // ---- prefetch next tile's fragments (hidden under softmax/PV)
        if (kt + 1 < 16) {
            const u16* Kt1 = Kp + (size_t)((kt + 1) * 64) * 64;
            const u16* Vt1 = Vp + (size_t)(kt + 1) * 64;
#pragma unroll
            for (int kf = 0; kf < 4; ++kf)
#pragma unroll
                for (int kh = 0; kh < 2; ++kh) {
                    ak[nb][kf][kh] = *(const bf16x8*)(Kt1 + (size_t)(kf * 16 + li) * 64 + kh * 32 + grp * 8);
                    av[nb][kf][kh] = *(const bf16x8*)(Vt1 + (size_t)(kf * 16 + li) * 1024 + kh * 32 + grp * 8);
                }
        }

        // ---- S^T = K Q^T : rows=keys (grp*4+r per kf), cols=q (li)
        f32x4 sf[2][4];
#pragma unroll
        for (int qf = 0; qf < 2; ++qf)
#pragma unroll
            for (int kf = 0; kf < 4; ++kf) {
                f32x4 acc = f32x4{0.f, 0.f, 0.f, 0.f};
                acc = __builtin_amdgcn_mfma_f32_16x16x32_bf16(ak[cb][kf][0], bq[qf][0], acc, 0, 0, 0);
                acc = __builtin_amdgcn_mfma_f32_16x16x32_bf16(ak[cb][kf][1], bq[qf][1], acc, 0, 0, 0);
                sf[qf][kf] = acc;
            }

        // ---- online softmax per qf (per-lane scalar state), base-2 exp
#pragma unroll
        for (int qf = 0; qf < 2; ++qf) {
            float mx = sf[qf][0][0];
#pragma unroll
            for (int kf = 0; kf < 4; ++kf)
#pragma unroll
                for (int r = 0; r < 4; ++r)
                    mx = fmaxf(mx, sf[qf][kf][r]);
            mx = fmaxf(mx, __shfl_xor(mx, 16));
            mx = fmaxf(mx, __shfl_xor(mx, 32));
            mx *= SM_SCALE;

            float mnew = fmaxf(mrun[qf], mx);
            float alpha = exp2f(mrun[qf] - mnew);
            mrun[qf] = mnew;

            float sum = 0.f;
#pragma unroll
            for (int kf = 0; kf < 4; ++kf) {
                ushort4 o;
                float p0 = exp2f(__builtin_fmaf(sf[qf][kf][0], SM_SCALE, -mnew));
                float p1 = exp2f(__builtin_fmaf(sf[qf][kf][1], SM_SCALE, -mnew));
                float p2 = exp2f(__builtin_fmaf(sf[qf][kf][2], SM_SCALE, -mnew));
                float p3 = exp2f(__builtin_fmaf(sf[qf][kf][3], SM_SCALE, -mnew));
                sum += (p0 + p1) + (p2 + p3);
                o.x = f2bf(p0); o.y = f2bf(p1); o.z = f2bf(p2); o.w = f2bf(p3);
                *(ushort4*)&Pt[qf][li][kf * 16 + grp * 4] = o;   // key=kf*16+grp*4+r
            }
            sum += __shfl_xor(sum, 16);
            sum += __shfl_xor(sum, 32);
            lrun[qf] = lrun[qf] * alpha + sum;
#pragma unroll
            for (int vf = 0; vf < 4; ++vf)
#pragma unroll
                for (int r = 0; r < 4; ++r)
                    oacc[qf][vf][r] *= alpha;
        }

        // ---- O^T += V P : A=V (m=v, k=key), B=P (n=q=li, k=key)
#pragma unroll
        for (int qf = 0; qf < 2; ++qf)
#pragma unroll
            for (int kh = 0; kh < 2; ++kh) {
                bf16x8 bp = *(const bf16x8*)&Pt[qf][li][kh * 32 + grp * 8];
#pragma unroll
                for (int vf = 0; vf < 4; ++vf)
                    oacc[qf][vf] = __builtin_amdgcn_mfma_f32_16x16x32_bf16(av[cb][vf][kh], bp, oacc[qf][vf], 0, 0, 0);
            }
    }

    // ---- epilogue: per-lane scale, stores with q on li (coalesced 64B/quad)
#pragma unroll
    for (int qf = 0; qf < 2; ++qf) {
        float invl = 1.f / lrun[qf];
        float* ob = out + (size_t)pair * 65536 + qt * 32 + qf * 16 + li;
#pragma unroll
        for (int vf = 0; vf < 4; ++vf)
#pragma unroll
            for (int r = 0; r < 4; ++r) {
                int v = vf * 16 + grp * 4 + r;
                ob[(size_t)v * 1024] = oacc[qf][vf][r] * invl;
            }
    }
}

extern "C" void kernel_launch(void* const* d_in, const int* in_sizes, int n_in,
                              void* d_out, int out_size, void* d_ws, size_t ws_size,
                              hipStream_t stream) {
    const float* x     = (const float*)d_in[0];
    const float* gamma = (const float*)d_in[1];
    const float* beta  = (const float*)d_in[2];
    float* out = (float*)d_out;

    float* partials = (float*)d_ws;                       // 3072 f32
    u16* Kn = (u16*)((char*)d_ws + 65536);                // 8.4 MB
    u16* Vn = Kn + (size_t)64 * 65536;                    // 8.4 MB (total ~16.8 MB)

    gn_partial<<<1536, 256, 0, stream>>>(x, partials);
    pack_kernel<<<1024, 256, 0, stream>>>(x, gamma, beta, partials, Kn, Vn);
    attn_kernel<<<2048, 64, 0, stream>>>(x, gamma, beta, partials, Kn, Vn, out);
}